// Round 8
// baseline (86.654 us; speedup 1.0000x reference)
//
#include <hip/hip_runtime.h>

// GaussianVectorQuantizer on MI355X: N=32768 rows, D=64, K=512, T=0.5
// out[0..2097151] = z_to_decoder [32][64][32][32], out[2097152]=loss, out[2097153]=perplexity
//
// Round 8: WG = one pair (128 threads, 2 waves). Round 7 kept occupancy pinned at
//          ~1 big WG/CU; now 8 independent 2-wave WGs/CU hide barrier+HBM latency.
//          pr: 2048 WGs fold 4->1 into the proven 512 slot arrays (4-way atomics).
//
// ws layout (floats) — max index identical to round 7's proven threshold:
//   [0..511]          hp*||c_k||^2
//   [512]             loss accumulator          (atomic fallback)
//   [516..1027]       avg-prob accumulator      (atomic fallback)
//   [4096..20479]     B1 fragments (64 KB)
//   [20480..36863]    B2 fragments (64 KB)
//   [36864..299007]   avg-prob slots (512 x 512), zeroed in k_pre, 4 WGs atomicAdd each
//   [299008..301055]  per-WG loss (2048, plain stores)
//   [303104..319487]  k_red partials (32 x 512)

typedef _Float16 half8 __attribute__((ext_vector_type(8)));
typedef float f32x4 __attribute__((ext_vector_type(4)));

#define WS_B1   4096
#define WS_B2   20480
#define WS_PROB 36864
#define WS_LOSS 299008
#define WS_RED  303104
#define WS_NEED 319488

#define SMEM_PRE 7680
#define SMEM_FB  138752

__device__ __forceinline__ float half_prec(const float* var_q) {
  float vq = var_q[0];
  float pq = fminf(1.0f / fmaxf(vq, 1e-5f), 1e5f);
  return 0.5f * pq;
}

// grid 16 x 512: norms, fallback-acc zeroing, fragment formatting, prob-slot zeroing
__global__ void k_pre(const float* __restrict__ var_q,
                      const float* __restrict__ cb,
                      float* __restrict__ ws, int pre) {
  int t = threadIdx.x, wg = blockIdx.x;
  int gid = wg * 512 + t;          // 0..8191
  if (wg == 0) {
    float hp = half_prec(var_q);
    if (t == 0) ws[512] = 0.0f;
    ws[516 + t] = 0.0f;
    const float4* row = (const float4*)(cb + t * 64);
    float s = 0.0f;
    #pragma unroll
    for (int i = 0; i < 16; ++i) {
      float4 v = row[i];
      s += v.x*v.x + v.y*v.y + v.z*v.z + v.w*v.w;
    }
    ws[t] = hp * s;
  }
  if (!pre) return;
  // zero the 512x512 prob-slot region (atomically accumulated each launch)
  #pragma unroll
  for (int i = 0; i < 32; ++i) ws[WS_PROB + gid + 8192*i] = 0.0f;
  if (gid < 4096) {
    // B1[tt*2+kk][l][j] = f16 cb[code=(l&15)*32+tt][dim=32*kk+8*(l>>4)+j]
    int l = gid & 63, grp = gid >> 6;
    int tt = grp >> 1, kk = grp & 1;
    int cc = l & 15, gg = l >> 4;
    const float* src = cb + (cc*32 + tt)*64 + kk*32 + gg*8;
    float4 v0 = *(const float4*)src;
    float4 v1 = *(const float4*)(src + 4);
    half8 h = { (_Float16)v0.x, (_Float16)v0.y, (_Float16)v0.z, (_Float16)v0.w,
                (_Float16)v1.x, (_Float16)v1.y, (_Float16)v1.z, (_Float16)v1.w };
    ((half8*)(ws + WS_B1))[gid] = h;
  } else {
    // B2[kt*4+nt][l][j] = f16 cb[code=((kap&15)<<5)+2*kt+(kap>>4)][dim=nt*16+(l&15)], kap=8*(l>>4)+j
    int F = gid - 4096;
    int l = F & 63, grp = F >> 6;
    int kt = grp >> 2, nt = grp & 3;
    int cc = l & 15, gg = l >> 4;
    int dim = nt*16 + cc;
    half8 h;
    #pragma unroll
    for (int j = 0; j < 8; ++j) {
      int kap = gg*8 + j;
      int code = ((kap & 15) << 5) + 2*kt + (kap >> 4);
      h[j] = (_Float16)cb[code*64 + dim];
    }
    ((half8*)(ws + WS_B2))[F] = h;
  }
}

template <int PRE>
__global__ __launch_bounds__(128) void k_main_t(
    const float* __restrict__ z, const float* __restrict__ vq,
    const float* __restrict__ cb, const float* __restrict__ gu,
    float* __restrict__ out, float* __restrict__ ws)
{
  extern __shared__ char smem[];
  constexpr int CB = PRE ? 0 : 131072;
  char*  chunk = smem + CB;                      // 5120 B: zc / eS / zqx overlays
  float* pr    = (float*)(smem + CB + 5120);     // 512 f32
  float* redM  = (float*)(smem + CB + 7168);     // 32 f32
  float* redS  = (float*)(smem + CB + 7296);     // 32 f32
  float* redP  = (float*)(smem + CB + 7424);     // 32 f32

  const int tid  = threadIdx.x;   // 128
  const int lane = tid & 63;
  const int h    = tid >> 6;      // wave = code half: (code&31) in [16h, 16h+16)
  const int c    = lane & 15;
  const int g    = lane >> 4;

  #pragma unroll
  for (int i = 0; i < 4; ++i) pr[tid + 128*i] = 0.0f;

  const half8* B1;
  const half8* B2;
  if constexpr (PRE) {
    B1 = (const half8*)(ws + WS_B1);
    B2 = (const half8*)(ws + WS_B2);
  } else {
    _Float16* lB1 = (_Float16*)smem;
    _Float16* lB2 = (_Float16*)(smem + 65536);
    for (int i = 0; i < 32; ++i) {
      int F = tid + 128*i;
      int l = F & 63, grp = F >> 6;
      int t = grp >> 1, kk = grp & 1;
      int cc = l & 15, gg = l >> 4;
      const float* src = cb + (cc*32 + t)*64 + kk*32 + gg*8;
      float4 v0 = *(const float4*)src;
      float4 v1 = *(const float4*)(src + 4);
      half8 hh = { (_Float16)v0.x, (_Float16)v0.y, (_Float16)v0.z, (_Float16)v0.w,
                   (_Float16)v1.x, (_Float16)v1.y, (_Float16)v1.z, (_Float16)v1.w };
      ((half8*)lB1)[F] = hh;
    }
    for (int i = 0; i < 32; ++i) {
      int F = tid + 128*i;
      int l = F & 63, grp = F >> 6;
      int kt = grp >> 2, nt = grp & 3;
      int cc = l & 15, gg = l >> 4;
      int dim = nt*16 + cc;
      half8 hh;
      #pragma unroll
      for (int j = 0; j < 8; ++j) {
        int kap = gg*8 + j;
        int code = ((kap & 15) << 5) + 2*kt + (kap >> 4);
        hh[j] = (_Float16)cb[code*64 + dim];
      }
      ((half8*)lB2)[F] = hh;
    }
    B1 = (const half8*)lB1;
    B2 = (const half8*)lB2;
  }

  const float hp   = half_prec(vq);
  const float s2hp = 2.0f * hp;

  const int row0 = blockIdx.x * 16;    // one 16-row tile per WG
  const int b    = row0 >> 10;
  const int wh0  = row0 & 1023;

  _Float16* zc = (_Float16*)chunk;     // [16 rows][72 halfs]

  // ---- z: each wave loads & stages ITS 8 rows (lane = dim), coalesced ----
  float zr[8];
  {
    const float* zp = z + ((size_t)(b*64 + lane) << 10) + wh0 + 8*h;
    float4 v0 = *(const float4*)zp;
    float4 v1 = *(const float4*)(zp + 4);
    zr[0]=v0.x; zr[1]=v0.y; zr[2]=v0.z; zr[3]=v0.w;
    zr[4]=v1.x; zr[5]=v1.y; zr[6]=v1.z; zr[7]=v1.w;
  }
  #pragma unroll
  for (int s = 0; s < 8; ++s) zc[(8*h + s)*72 + lane] = (_Float16)(zr[s] * s2hp);

  __syncthreads();   // zc (+ pr init; FB: B1/B2) visible across the pair

  // ---- acc init: -hp*||c_k||^2 for codes c*32 + h*16 + t ----
  f32x4 acc[16];
  {
    const float4* hn = (const float4*)(ws + c*32 + h*16);
    #pragma unroll
    for (int u = 0; u < 4; ++u) {
      float4 h4 = hn[u];
      acc[4*u+0] = (f32x4){-h4.x, -h4.x, -h4.x, -h4.x};
      acc[4*u+1] = (f32x4){-h4.y, -h4.y, -h4.y, -h4.y};
      acc[4*u+2] = (f32x4){-h4.z, -h4.z, -h4.z, -h4.z};
      acc[4*u+3] = (f32x4){-h4.w, -h4.w, -h4.w, -h4.w};
    }
  }

  half8 zA0 = *(const half8*)(zc + c*72 + g*8);
  half8 zA1 = *(const half8*)(zc + c*72 + 32 + g*8);

  // ---- pass 1: 32 MFMA -> acc[t][q] = logit[row 4g+q][code c*32+h*16+t] ----
  #pragma unroll
  for (int t = 0; t < 16; ++t) {
    int tt = h*16 + t;
    acc[t] = __builtin_amdgcn_mfma_f32_16x16x32_f16(zA0, B1[(tt*2+0)*64 + lane], acc[t], 0, 0, 0);
    acc[t] = __builtin_amdgcn_mfma_f32_16x16x32_f16(zA1, B1[(tt*2+1)*64 + lane], acc[t], 0, 0, 0);
  }

  const int rix = h*16;

  // ---- softmax max: intra-wave (16 c-lanes) then cross-half via LDS ----
  #pragma unroll
  for (int q = 0; q < 4; ++q) {
    float m = acc[0][q];
    #pragma unroll
    for (int t = 1; t < 16; ++t) m = fmaxf(m, acc[t][q]);
    #pragma unroll
    for (int o = 8; o > 0; o >>= 1) m = fmaxf(m, __shfl_xor(m, o));
    if (c == 0) redM[rix + 4*g + q] = m;
  }
  __syncthreads();
  float mq[4];
  #pragma unroll
  for (int q = 0; q < 4; ++q)
    mq[q] = fmaxf(redM[4*g + q], redM[16 + 4*g + q]);
  #pragma unroll
  for (int t = 0; t < 16; ++t)
    #pragma unroll
    for (int q = 0; q < 4; ++q) acc[t][q] -= mq[q];

  // ---- exp-sums (s1) and p*logit sums (pl) ----
  {
    float s1[4] = {0,0,0,0}, pl[4] = {0,0,0,0};
    #pragma unroll
    for (int t = 0; t < 16; ++t)
      #pragma unroll
      for (int q = 0; q < 4; ++q) {
        float e = __expf(acc[t][q]);
        s1[q] += e;
        pl[q] = fmaf(e, acc[t][q], pl[q]);
      }
    #pragma unroll
    for (int q = 0; q < 4; ++q) {
      #pragma unroll
      for (int o = 8; o > 0; o >>= 1) { s1[q] += __shfl_xor(s1[q], o); pl[q] += __shfl_xor(pl[q], o); }
      if (c == 0) { redS[rix + 4*g + q] = s1[q]; redP[rix + 4*g + q] = pl[q]; }
    }
  }
  __syncthreads();
  float kd = 0.0f, inv1[4];
  #pragma unroll
  for (int q = 0; q < 4; ++q) {
    float S = redS[4*g + q] + redS[16 + 4*g + q];
    float P = redP[4*g + q] + redP[16 + 4*g + q];
    inv1[q] = 1.0f / S;
    kd += P * inv1[q] - __logf(S);
  }

  // ---- avg-prob accumulation: code c*32+h*16+t -> pr[(h*16+t)*16 + c] ----
  #pragma unroll
  for (int t = 0; t < 16; ++t) {
    float v = 0.0f;
    #pragma unroll
    for (int q = 0; q < 4; ++q) v = fmaf(__expf(acc[t][q]), inv1[q], v);
    v += __shfl_xor(v, 16);
    v += __shfl_xor(v, 32);
    if (g == 0) atomicAdd(&pr[(h*16 + t)*16 + c], v);
  }

  // ---- gumbel: acc <- 2*(l + gv), gv = -log(-log(u+eps)+eps) ----
  #pragma unroll
  for (int q = 0; q < 4; ++q) {
    const float4* ub = (const float4*)(gu + ((size_t)(row0 + 4*g + q))*512 + c*32 + h*16);
    #pragma unroll
    for (int tt = 0; tt < 4; ++tt) {
      float4 u4 = ub[tt];
      float y0 = 1e-10f - __logf(u4.x + 1e-10f);
      float y1 = 1e-10f - __logf(u4.y + 1e-10f);
      float y2 = 1e-10f - __logf(u4.z + 1e-10f);
      float y3 = 1e-10f - __logf(u4.w + 1e-10f);
      acc[4*tt+0][q] = 2.0f * (acc[4*tt+0][q] - __logf(y0));
      acc[4*tt+1][q] = 2.0f * (acc[4*tt+1][q] - __logf(y1));
      acc[4*tt+2][q] = 2.0f * (acc[4*tt+2][q] - __logf(y2));
      acc[4*tt+3][q] = 2.0f * (acc[4*tt+3][q] - __logf(y3));
    }
  }

  // ---- encoding softmax: max then sum, cross-half combined ----
  #pragma unroll
  for (int q = 0; q < 4; ++q) {
    float m = acc[0][q];
    #pragma unroll
    for (int t = 1; t < 16; ++t) m = fmaxf(m, acc[t][q]);
    #pragma unroll
    for (int o = 8; o > 0; o >>= 1) m = fmaxf(m, __shfl_xor(m, o));
    if (c == 0) redM[rix + 4*g + q] = m;
  }
  __syncthreads();
  #pragma unroll
  for (int q = 0; q < 4; ++q) {
    float m2 = fmaxf(redM[4*g + q], redM[16 + 4*g + q]);
    float s = 0.0f;
    #pragma unroll
    for (int t = 0; t < 16; ++t) { float e = __expf(acc[t][q] - m2); acc[t][q] = e; s += e; }
    #pragma unroll
    for (int o = 8; o > 0; o >>= 1) s += __shfl_xor(s, o);
    if (c == 0) redS[rix + 4*g + q] = s;
  }
  __syncthreads();
  #pragma unroll
  for (int q = 0; q < 4; ++q) {
    float inv = 1.0f / (redS[4*g + q] + redS[16 + 4*g + q]);
    #pragma unroll
    for (int t = 0; t < 16; ++t) acc[t][q] *= inv;
  }

  // ---- pass 2: partial zq over this wave's 256 codes ----
  f32x4 zacc[4];
  #pragma unroll
  for (int nt = 0; nt < 4; ++nt) zacc[nt] = (f32x4){0.f, 0.f, 0.f, 0.f};

  _Float16* myES = (_Float16*)(chunk + h * 2560);
  #pragma unroll
  for (int k = 0; k < 8; ++k) {
    _Float16* eS = myES + (k & 1) * 640;     // [16 rows][40 halfs], wave-private
    #pragma unroll
    for (int tb = 0; tb < 2; ++tb)
      #pragma unroll
      for (int q = 0; q < 4; ++q)
        eS[(4*g + q)*40 + 16*tb + c] = (_Float16)acc[2*k + tb][q];
    half8 ea = *(const half8*)(eS + c*40 + g*8);
    int kt = h*8 + k;
    #pragma unroll
    for (int nt = 0; nt < 4; ++nt)
      zacc[nt] = __builtin_amdgcn_mfma_f32_16x16x32_f16(ea, B2[(kt*4 + nt)*64 + lane], zacc[nt], 0, 0, 0);
  }

  // ---- pair-sum zq through LDS, transpose-store + continuous KLD ----
  __syncthreads();
  float* zqx = (float*)chunk;                // [16 rows][66 f32]
  if (h) {
    #pragma unroll
    for (int nt = 0; nt < 4; ++nt)
      #pragma unroll
      for (int q = 0; q < 4; ++q)
        zqx[(4*g + q)*66 + nt*16 + c] = zacc[nt][q];
  }
  __syncthreads();
  if (!h) {
    #pragma unroll
    for (int nt = 0; nt < 4; ++nt)
      #pragma unroll
      for (int q = 0; q < 4; ++q) {
        int ix = (4*g + q)*66 + nt*16 + c;
        zqx[ix] += zacc[nt][q];
      }
  }
  __syncthreads();

  float kc = 0.0f;
  {
    float* orow = out + ((size_t)(b*64 + lane) << 10) + wh0 + 8*h;
    float4 o0, o1;
    o0.x = zqx[(8*h + 0)*66 + lane]; o0.y = zqx[(8*h + 1)*66 + lane];
    o0.z = zqx[(8*h + 2)*66 + lane]; o0.w = zqx[(8*h + 3)*66 + lane];
    o1.x = zqx[(8*h + 4)*66 + lane]; o1.y = zqx[(8*h + 5)*66 + lane];
    o1.z = zqx[(8*h + 6)*66 + lane]; o1.w = zqx[(8*h + 7)*66 + lane];
    float d;
    d = zr[0]-o0.x; kc = fmaf(d,d,kc);  d = zr[1]-o0.y; kc = fmaf(d,d,kc);
    d = zr[2]-o0.z; kc = fmaf(d,d,kc);  d = zr[3]-o0.w; kc = fmaf(d,d,kc);
    d = zr[4]-o1.x; kc = fmaf(d,d,kc);  d = zr[5]-o1.y; kc = fmaf(d,d,kc);
    d = zr[6]-o1.z; kc = fmaf(d,d,kc);  d = zr[7]-o1.w; kc = fmaf(d,d,kc);
    *(float4*)orow       = o0;
    *(float4*)(orow + 4) = o1;
  }
  kc *= hp;

  // ---- loss partial: kd only from h==0 (dup x16 c-lanes), kc from both ----
  float lv = (h ? 0.0f : kd * 0.0625f) + kc;
  #pragma unroll
  for (int o = 32; o > 0; o >>= 1) lv += __shfl_xor(lv, o);
  if (lane == 0) redP[h] = lv;          // redP done with stats duty
  __syncthreads();

  if constexpr (PRE) {
    if (tid == 0) ws[WS_LOSS + blockIdx.x] = redP[0] + redP[1];
    int slot = blockIdx.x >> 2;         // 4 WGs fold into one slot array
    #pragma unroll
    for (int i = 0; i < 4; ++i) {
      int k = tid + 128*i;
      atomicAdd(&ws[WS_PROB + slot*512 + k], pr[k]);
    }
  } else {
    if (tid == 0) atomicAdd(&ws[512], redP[0] + redP[1]);
    #pragma unroll
    for (int i = 0; i < 4; ++i) {
      int k = tid + 128*i;
      atomicAdd(ws + 516 + k, pr[k]);
    }
  }
}

__global__ void k_red(float* __restrict__ ws) {
  int gix = blockIdx.x, t = threadIdx.x;   // 32 x 512
  float s = 0.0f;
  #pragma unroll 4
  for (int i = 0; i < 16; ++i) s += ws[WS_PROB + (size_t)(gix*16 + i)*512 + t];
  ws[WS_RED + gix*512 + t] = s;
}

__global__ void k_fin(const float* __restrict__ ws, float* __restrict__ out, int pre) {
  __shared__ float redH[16], redL[16];
  int t = threadIdx.x;  // 1024
  float h = 0.0f, l = 0.0f;
  if (pre) {
    if (t < 512) {
      float s = 0.0f;
      #pragma unroll
      for (int g = 0; g < 32; ++g) s += ws[WS_RED + g*512 + t];
      float a = fmaxf(s * (1.0f/32768.0f), 1e-10f);
      h = -a * __logf(a + 1e-10f);
    } else {
      int x = t - 512;
      #pragma unroll
      for (int i = 0; i < 4; ++i) l += ws[WS_LOSS + x + 512*i];
    }
  } else {
    if (t < 512) {
      float a = fmaxf(ws[516 + t] * (1.0f/32768.0f), 1e-10f);
      h = -a * __logf(a + 1e-10f);
    } else if (t == 512) {
      l = ws[512];
    }
  }
  #pragma unroll
  for (int o = 32; o > 0; o >>= 1) { h += __shfl_xor(h, o); l += __shfl_xor(l, o); }
  if ((t & 63) == 0) { redH[t >> 6] = h; redL[t >> 6] = l; }
  __syncthreads();
  if (t == 0) {
    float H = 0.0f, L = 0.0f;
    #pragma unroll
    for (int i = 0; i < 16; ++i) { H += redH[i]; L += redL[i]; }
    out[2097152] = L * (1.0f/32.0f);
    out[2097153] = __expf(H);
  }
}

extern "C" void kernel_launch(void* const* d_in, const int* in_sizes, int n_in,
                              void* d_out, int out_size, void* d_ws, size_t ws_size,
                              hipStream_t stream) {
  const float* z  = (const float*)d_in[0];
  const float* vq = (const float*)d_in[1];
  const float* cb = (const float*)d_in[2];
  const float* gu = (const float*)d_in[3];
  float* out = (float*)d_out;
  float* ws  = (float*)d_ws;
  int pre = (ws_size >= (size_t)WS_NEED * 4) ? 1 : 0;

  hipLaunchKernelGGL(k_pre, dim3(16), dim3(512), 0, stream, vq, cb, ws, pre);
  if (pre) {
    hipLaunchKernelGGL(k_main_t<1>, dim3(2048), dim3(128), SMEM_PRE, stream, z, vq, cb, gu, out, ws);
    hipLaunchKernelGGL(k_red, dim3(32), dim3(512), 0, stream, ws);
  } else {
    hipFuncSetAttribute((const void*)&k_main_t<0>, hipFuncAttributeMaxDynamicSharedMemorySize, SMEM_FB);
    hipLaunchKernelGGL(k_main_t<0>, dim3(2048), dim3(128), SMEM_FB, stream, z, vq, cb, gu, out, ws);
  }
  hipLaunchKernelGGL(k_fin, dim3(1), dim3(1024), 0, stream, ws, out, pre);
}

// Round 9
// 62.238 us; speedup vs baseline: 1.3923x; 1.3923x over previous
//
#include <hip/hip_runtime.h>

// GaussianVectorQuantizer on MI355X: N=32768 rows, D=64, K=512, T=0.5
// out[0..2097151] = z_to_decoder [32][64][32][32], out[2097152]=loss, out[2097153]=perplexity
//
// Round 9: round-7 topology (512x512, best at 62us) + VALU/trans diet:
//   (a) stats loop overwrites acc with p=exp(l') -> avg-prob phase needs no exp;
//   (b) gumbel-softmax via e = p^2 * y^-2 (y = eps - log(u+eps)): no second log,
//       no exp, no max phase (stable since row-max term has p=1, y<=23).
//   Trans stream 320 -> 192 per wave, one barrier fewer, zero VGPR cost.
//
// ws layout (floats):
//   [0..511]          hp*||c_k||^2
//   [512]             loss accumulator          (atomic fallback)
//   [516..1027]       avg-prob accumulator      (atomic fallback)
//   [4096..20479]     B1 fragments (64 KB)      (pre mode)
//   [20480..36863]    B2 fragments (64 KB)      (pre mode)
//   [36864..299007]   per-WG avg-prob partials  (pre: wg*512 + tid, 512 WGs)
//   [299008..303103]  per-wave loss partials    (pre: wg*8 + wave)
//   [303104..319487]  k_red partials            (32 x 512)

typedef _Float16 half8 __attribute__((ext_vector_type(8)));
typedef float f32x4 __attribute__((ext_vector_type(4)));

#define WS_B1   4096
#define WS_B2   20480
#define WS_PROB 36864
#define WS_LOSS 299008
#define WS_RED  303104
#define WS_NEED 319488

#define SMEM_PRE 24064
#define SMEM_FB  155136

__device__ __forceinline__ float half_prec(const float* var_q) {
  float vq = var_q[0];
  float pq = fminf(1.0f / fmaxf(vq, 1e-5f), 1e5f);
  return 0.5f * pq;
}

// grid 16 x 512: WG0 does norms + atomic-mode zeroing; all WGs format fragments (pre mode)
__global__ void k_pre(const float* __restrict__ var_q,
                      const float* __restrict__ cb,
                      float* __restrict__ ws, int pre) {
  int t = threadIdx.x, wg = blockIdx.x;
  if (wg == 0) {
    float hp = half_prec(var_q);
    if (t == 0) ws[512] = 0.0f;
    ws[516 + t] = 0.0f;
    const float4* row = (const float4*)(cb + t * 64);
    float s = 0.0f;
    #pragma unroll
    for (int i = 0; i < 16; ++i) {
      float4 v = row[i];
      s += v.x*v.x + v.y*v.y + v.z*v.z + v.w*v.w;
    }
    ws[t] = hp * s;
  }
  if (!pre) return;
  int gid = wg * 512 + t;          // 0..8191
  if (gid < 4096) {
    // B1[tt*2+kk][l][j] = f16 cb[code=(l&15)*32+tt][dim=32*kk+8*(l>>4)+j]
    int l = gid & 63, grp = gid >> 6;
    int tt = grp >> 1, kk = grp & 1;
    int cc = l & 15, gg = l >> 4;
    const float* src = cb + (cc*32 + tt)*64 + kk*32 + gg*8;
    float4 v0 = *(const float4*)src;
    float4 v1 = *(const float4*)(src + 4);
    half8 h = { (_Float16)v0.x, (_Float16)v0.y, (_Float16)v0.z, (_Float16)v0.w,
                (_Float16)v1.x, (_Float16)v1.y, (_Float16)v1.z, (_Float16)v1.w };
    ((half8*)(ws + WS_B1))[gid] = h;
  } else {
    // B2[kt*4+nt][l][j] = f16 cb[code=((kap&15)<<5)+2*kt+(kap>>4)][dim=nt*16+(l&15)], kap=8*(l>>4)+j
    int F = gid - 4096;
    int l = F & 63, grp = F >> 6;
    int kt = grp >> 2, nt = grp & 3;
    int cc = l & 15, gg = l >> 4;
    int dim = nt*16 + cc;
    half8 h;
    #pragma unroll
    for (int j = 0; j < 8; ++j) {
      int kap = gg*8 + j;
      int code = ((kap & 15) << 5) + 2*kt + (kap >> 4);
      h[j] = (_Float16)cb[code*64 + dim];
    }
    ((half8*)(ws + WS_B2))[F] = h;
  }
}

template <int PRE>
__global__ __launch_bounds__(512) void k_main_t(
    const float* __restrict__ z, const float* __restrict__ vq,
    const float* __restrict__ cb, const float* __restrict__ gu,
    float* __restrict__ out, float* __restrict__ ws)
{
  extern __shared__ char smem[];
  constexpr int CB = PRE ? 0 : 131072;
  char*  chunkAll = smem + CB;                   // 20480 B: zc (pair) / eS (wave) / zqx (pair)
  float* pr   = (float*)(smem + CB + 20480);     // 512 f32
  float* redM = (float*)(smem + CB + 22528);     // [4 pairs][2 halves][16 rows]
  float* redS = (float*)(smem + CB + 23040);
  float* redP = (float*)(smem + CB + 23552);

  const int tid  = threadIdx.x;
  const int lane = tid & 63;
  const int wv   = tid >> 6;
  const int h    = wv & 1;        // code half: (code&31) in [16h, 16h+16)
  const int p    = wv >> 1;       // row-tile pair index (0..3)
  const int c    = lane & 15;
  const int g    = lane >> 4;

  pr[tid] = 0.0f;

  const half8* B1;
  const half8* B2;
  if constexpr (PRE) {
    B1 = (const half8*)(ws + WS_B1);
    B2 = (const half8*)(ws + WS_B2);
  } else {
    // in-LDS staging fallback
    _Float16* lB1 = (_Float16*)smem;
    _Float16* lB2 = (_Float16*)(smem + 65536);
    #pragma unroll
    for (int i = 0; i < 8; ++i) {
      int F = tid + 512*i;
      int l = F & 63, grp = F >> 6;
      int t = grp >> 1, kk = grp & 1;
      int cc = l & 15, gg = l >> 4;
      const float* src = cb + (cc*32 + t)*64 + kk*32 + gg*8;
      float4 v0 = *(const float4*)src;
      float4 v1 = *(const float4*)(src + 4);
      half8 hh = { (_Float16)v0.x, (_Float16)v0.y, (_Float16)v0.z, (_Float16)v0.w,
                   (_Float16)v1.x, (_Float16)v1.y, (_Float16)v1.z, (_Float16)v1.w };
      ((half8*)lB1)[F] = hh;
    }
    #pragma unroll
    for (int i = 0; i < 8; ++i) {
      int F = tid + 512*i;
      int l = F & 63, grp = F >> 6;
      int kt = grp >> 2, nt = grp & 3;
      int cc = l & 15, gg = l >> 4;
      int dim = nt*16 + cc;
      half8 hh;
      #pragma unroll
      for (int j = 0; j < 8; ++j) {
        int kap = gg*8 + j;
        int code = ((kap & 15) << 5) + 2*kt + (kap >> 4);
        hh[j] = (_Float16)cb[code*64 + dim];
      }
      ((half8*)lB2)[F] = hh;
    }
    B1 = (const half8*)lB1;
    B2 = (const half8*)lB2;
  }

  const float hp   = half_prec(vq);
  const float s2hp = 2.0f * hp;

  const int row0 = (blockIdx.x * 4 + p) * 16;    // 16 rows per PAIR
  const int b    = row0 >> 10;
  const int wh0  = row0 & 1023;

  _Float16* zc = (_Float16*)(chunkAll + p * 5120);   // [16 rows][72 halfs], pair-shared

  // ---- z: each wave loads & stages ITS 8 rows (lane = dim), coalesced ----
  float zr[8];
  {
    const float* zp = z + ((size_t)(b*64 + lane) << 10) + wh0 + 8*h;
    float4 v0 = *(const float4*)zp;
    float4 v1 = *(const float4*)(zp + 4);
    zr[0]=v0.x; zr[1]=v0.y; zr[2]=v0.z; zr[3]=v0.w;
    zr[4]=v1.x; zr[5]=v1.y; zr[6]=v1.z; zr[7]=v1.w;
  }
  #pragma unroll
  for (int s = 0; s < 8; ++s) zc[(8*h + s)*72 + lane] = (_Float16)(zr[s] * s2hp);

  __syncthreads();   // zc (and, in FB, B1/B2) visible

  // ---- acc init: -hp*||c_k||^2 for codes c*32 + h*16 + t ----
  f32x4 acc[16];
  {
    const float4* hn = (const float4*)(ws + c*32 + h*16);
    #pragma unroll
    for (int u = 0; u < 4; ++u) {
      float4 h4 = hn[u];
      acc[4*u+0] = (f32x4){-h4.x, -h4.x, -h4.x, -h4.x};
      acc[4*u+1] = (f32x4){-h4.y, -h4.y, -h4.y, -h4.y};
      acc[4*u+2] = (f32x4){-h4.z, -h4.z, -h4.z, -h4.z};
      acc[4*u+3] = (f32x4){-h4.w, -h4.w, -h4.w, -h4.w};
    }
  }

  half8 zA0 = *(const half8*)(zc + c*72 + g*8);
  half8 zA1 = *(const half8*)(zc + c*72 + 32 + g*8);

  // ---- pass 1: 32 MFMA -> acc[t][q] = logit[row 4g+q][code c*32+h*16+t] ----
  #pragma unroll
  for (int t = 0; t < 16; ++t) {
    int tt = h*16 + t;
    acc[t] = __builtin_amdgcn_mfma_f32_16x16x32_f16(zA0, B1[(tt*2+0)*64 + lane], acc[t], 0, 0, 0);
    acc[t] = __builtin_amdgcn_mfma_f32_16x16x32_f16(zA1, B1[(tt*2+1)*64 + lane], acc[t], 0, 0, 0);
  }

  const int rix = p*32 + h*16;

  // ---- softmax max: intra-wave then cross-half via LDS ----
  #pragma unroll
  for (int q = 0; q < 4; ++q) {
    float m = acc[0][q];
    #pragma unroll
    for (int t = 1; t < 16; ++t) m = fmaxf(m, acc[t][q]);
    #pragma unroll
    for (int o = 8; o > 0; o >>= 1) m = fmaxf(m, __shfl_xor(m, o));
    if (c == 0) redM[rix + 4*g + q] = m;
  }
  __syncthreads();
  float mq[4];
  #pragma unroll
  for (int q = 0; q < 4; ++q)
    mq[q] = fmaxf(redM[p*32 + 4*g + q], redM[p*32 + 16 + 4*g + q]);

  // ---- stats: p = exp(l'), s1 = sum p, pl = sum p*l'; acc <- p (l' dead after) ----
  {
    float s1[4] = {0,0,0,0}, pl[4] = {0,0,0,0};
    #pragma unroll
    for (int t = 0; t < 16; ++t)
      #pragma unroll
      for (int q = 0; q < 4; ++q) {
        float l = acc[t][q] - mq[q];
        float e = __expf(l);
        s1[q] += e;
        pl[q] = fmaf(e, l, pl[q]);
        acc[t][q] = e;               // cache p
      }
    #pragma unroll
    for (int q = 0; q < 4; ++q) {
      #pragma unroll
      for (int o = 8; o > 0; o >>= 1) { s1[q] += __shfl_xor(s1[q], o); pl[q] += __shfl_xor(pl[q], o); }
      if (c == 0) { redS[rix + 4*g + q] = s1[q]; redP[rix + 4*g + q] = pl[q]; }
    }
  }
  __syncthreads();
  float kd = 0.0f, inv1[4];
  #pragma unroll
  for (int q = 0; q < 4; ++q) {
    float S = redS[p*32 + 4*g + q] + redS[p*32 + 16 + 4*g + q];
    float P = redP[p*32 + 4*g + q] + redP[p*32 + 16 + 4*g + q];
    inv1[q] = 1.0f / S;
    kd += P * inv1[q] - __logf(S);
  }

  // ---- avg-prob accumulation from cached p: code c*32+h*16+t -> pr[(h*16+t)*16+c] ----
  #pragma unroll
  for (int t = 0; t < 16; ++t) {
    float v = 0.0f;
    #pragma unroll
    for (int q = 0; q < 4; ++q) v = fmaf(acc[t][q], inv1[q], v);
    v += __shfl_xor(v, 16);
    v += __shfl_xor(v, 32);
    if (g == 0) atomicAdd(&pr[(h*16 + t)*16 + c], v);
  }

  // ---- gumbel-softmax numerators: e = p^2 * y^-2, y = eps - log(u+eps) ----
  // (== exp(2(l'+g)); no max subtraction needed: row-max term has p=1, y<=23.03)
  #pragma unroll
  for (int q = 0; q < 4; ++q) {
    const float4* ub = (const float4*)(gu + ((size_t)(row0 + 4*g + q))*512 + c*32 + h*16);
    #pragma unroll
    for (int tt = 0; tt < 4; ++tt) {
      float4 u4 = ub[tt];
      float y0 = 1e-10f - __logf(u4.x + 1e-10f);
      float y1 = 1e-10f - __logf(u4.y + 1e-10f);
      float y2 = 1e-10f - __logf(u4.z + 1e-10f);
      float y3 = 1e-10f - __logf(u4.w + 1e-10f);
      float r0 = __builtin_amdgcn_rcpf(y0*y0);
      float r1 = __builtin_amdgcn_rcpf(y1*y1);
      float r2 = __builtin_amdgcn_rcpf(y2*y2);
      float r3 = __builtin_amdgcn_rcpf(y3*y3);
      float a0 = acc[4*tt+0][q], a1 = acc[4*tt+1][q];
      float a2 = acc[4*tt+2][q], a3 = acc[4*tt+3][q];
      acc[4*tt+0][q] = a0*a0*r0;
      acc[4*tt+1][q] = a1*a1*r1;
      acc[4*tt+2][q] = a2*a2*r2;
      acc[4*tt+3][q] = a3*a3*r3;
    }
  }

  __syncthreads();   // all waves done reading redS/redP before rewrite

  // ---- encoding normalization: s = sum e (cross-half), acc <- e/s ----
  #pragma unroll
  for (int q = 0; q < 4; ++q) {
    float s = 0.0f;
    #pragma unroll
    for (int t = 0; t < 16; ++t) s += acc[t][q];
    #pragma unroll
    for (int o = 8; o > 0; o >>= 1) s += __shfl_xor(s, o);
    if (c == 0) redS[rix + 4*g + q] = s;
  }
  __syncthreads();
  #pragma unroll
  for (int q = 0; q < 4; ++q) {
    float inv = 1.0f / (redS[p*32 + 4*g + q] + redS[p*32 + 16 + 4*g + q]);
    #pragma unroll
    for (int t = 0; t < 16; ++t) acc[t][q] *= inv;
  }

  // ---- pass 2: partial zq over this wave's 256 codes ----
  f32x4 zacc[4];
  #pragma unroll
  for (int nt = 0; nt < 4; ++nt) zacc[nt] = (f32x4){0.f, 0.f, 0.f, 0.f};

  _Float16* myES = (_Float16*)(chunkAll + wv * 2560);
  #pragma unroll
  for (int k = 0; k < 8; ++k) {
    _Float16* eS = myES + (k & 1) * 640;     // [16 rows][40 halfs], wave-private
    #pragma unroll
    for (int tb = 0; tb < 2; ++tb)
      #pragma unroll
      for (int q = 0; q < 4; ++q)
        eS[(4*g + q)*40 + 16*tb + c] = (_Float16)acc[2*k + tb][q];
    half8 ea = *(const half8*)(eS + c*40 + g*8);
    int kt = h*8 + k;
    #pragma unroll
    for (int nt = 0; nt < 4; ++nt)
      zacc[nt] = __builtin_amdgcn_mfma_f32_16x16x32_f16(ea, B2[(kt*4 + nt)*64 + lane], zacc[nt], 0, 0, 0);
  }

  // ---- pair-sum zq through LDS, transpose-store + continuous KLD ----
  __syncthreads();
  float* zqx = (float*)chunkAll + p * 1056;          // [16 rows][66 f32], pair-shared
  if (h) {
    #pragma unroll
    for (int nt = 0; nt < 4; ++nt)
      #pragma unroll
      for (int q = 0; q < 4; ++q)
        zqx[(4*g + q)*66 + nt*16 + c] = zacc[nt][q];
  }
  __syncthreads();
  if (!h) {
    #pragma unroll
    for (int nt = 0; nt < 4; ++nt)
      #pragma unroll
      for (int q = 0; q < 4; ++q) {
        int ix = (4*g + q)*66 + nt*16 + c;
        zqx[ix] += zacc[nt][q];
      }
  }
  __syncthreads();

  float kc = 0.0f;
  {
    float* orow = out + ((size_t)(b*64 + lane) << 10) + wh0 + 8*h;
    float4 o0, o1;
    o0.x = zqx[(8*h + 0)*66 + lane]; o0.y = zqx[(8*h + 1)*66 + lane];
    o0.z = zqx[(8*h + 2)*66 + lane]; o0.w = zqx[(8*h + 3)*66 + lane];
    o1.x = zqx[(8*h + 4)*66 + lane]; o1.y = zqx[(8*h + 5)*66 + lane];
    o1.z = zqx[(8*h + 6)*66 + lane]; o1.w = zqx[(8*h + 7)*66 + lane];
    float d;
    d = zr[0]-o0.x; kc = fmaf(d,d,kc);  d = zr[1]-o0.y; kc = fmaf(d,d,kc);
    d = zr[2]-o0.z; kc = fmaf(d,d,kc);  d = zr[3]-o0.w; kc = fmaf(d,d,kc);
    d = zr[4]-o1.x; kc = fmaf(d,d,kc);  d = zr[5]-o1.y; kc = fmaf(d,d,kc);
    d = zr[6]-o1.z; kc = fmaf(d,d,kc);  d = zr[7]-o1.w; kc = fmaf(d,d,kc);
    *(float4*)orow       = o0;
    *(float4*)(orow + 4) = o1;
  }
  kc *= hp;

  // ---- loss partial: kd only from h==0 (dup x16 c-lanes), kc from both ----
  float lv = (h ? 0.0f : kd * 0.0625f) + kc;
  #pragma unroll
  for (int o = 32; o > 0; o >>= 1) lv += __shfl_xor(lv, o);
  if (lane == 0) {
    if constexpr (PRE) ws[WS_LOSS + blockIdx.x*8 + wv] = lv;
    else               atomicAdd(&ws[512], lv);
  }

  __syncthreads();
  if constexpr (PRE) {
    ws[WS_PROB + (size_t)blockIdx.x*512 + tid] = pr[tid];
  } else {
    atomicAdd(ws + 516 + tid, pr[tid]);
  }
}

__global__ void k_red(float* __restrict__ ws) {
  int gix = blockIdx.x, t = threadIdx.x;   // 32 x 512
  float s = 0.0f;
  #pragma unroll 4
  for (int i = 0; i < 16; ++i) s += ws[WS_PROB + (size_t)(gix*16 + i)*512 + t];
  ws[WS_RED + gix*512 + t] = s;
}

__global__ void k_fin(const float* __restrict__ ws, float* __restrict__ out, int pre) {
  __shared__ float redH[16], redL[16];
  int t = threadIdx.x;  // 1024
  float h = 0.0f, l = 0.0f;
  if (pre) {
    if (t < 512) {
      float s = 0.0f;
      #pragma unroll
      for (int g = 0; g < 32; ++g) s += ws[WS_RED + g*512 + t];
      float a = fmaxf(s * (1.0f/32768.0f), 1e-10f);
      h = -a * __logf(a + 1e-10f);
    } else {
      int x = t - 512;
      #pragma unroll
      for (int i = 0; i < 8; ++i) l += ws[WS_LOSS + x + 512*i];
    }
  } else {
    if (t < 512) {
      float a = fmaxf(ws[516 + t] * (1.0f/32768.0f), 1e-10f);
      h = -a * __logf(a + 1e-10f);
    } else if (t == 512) {
      l = ws[512];
    }
  }
  #pragma unroll
  for (int o = 32; o > 0; o >>= 1) { h += __shfl_xor(h, o); l += __shfl_xor(l, o); }
  if ((t & 63) == 0) { redH[t >> 6] = h; redL[t >> 6] = l; }
  __syncthreads();
  if (t == 0) {
    float H = 0.0f, L = 0.0f;
    #pragma unroll
    for (int i = 0; i < 16; ++i) { H += redH[i]; L += redL[i]; }
    out[2097152] = L * (1.0f/32.0f);
    out[2097153] = __expf(H);
  }
}

extern "C" void kernel_launch(void* const* d_in, const int* in_sizes, int n_in,
                              void* d_out, int out_size, void* d_ws, size_t ws_size,
                              hipStream_t stream) {
  const float* z  = (const float*)d_in[0];
  const float* vq = (const float*)d_in[1];
  const float* cb = (const float*)d_in[2];
  const float* gu = (const float*)d_in[3];
  float* out = (float*)d_out;
  float* ws  = (float*)d_ws;
  int pre = (ws_size >= (size_t)WS_NEED * 4) ? 1 : 0;

  hipLaunchKernelGGL(k_pre, dim3(16), dim3(512), 0, stream, vq, cb, ws, pre);
  if (pre) {
    hipLaunchKernelGGL(k_main_t<1>, dim3(512), dim3(512), SMEM_PRE, stream, z, vq, cb, gu, out, ws);
    hipLaunchKernelGGL(k_red, dim3(32), dim3(512), 0, stream, ws);
  } else {
    hipFuncSetAttribute((const void*)&k_main_t<0>, hipFuncAttributeMaxDynamicSharedMemorySize, SMEM_FB);
    hipLaunchKernelGGL(k_main_t<0>, dim3(512), dim3(512), SMEM_FB, stream, z, vq, cb, gu, out, ws);
  }
  hipLaunchKernelGGL(k_fin, dim3(1), dim3(1024), 0, stream, ws, out, pre);
}